// Round 1
// baseline (215.635 us; speedup 1.0000x reference)
//
#include <hip/hip_runtime.h>

#define C_DIM 28
#define HW 65536   // 256*256
#define B_DIM 16

namespace {

constexpr double K_PI = 3.14159265358979323846;

// Taylor cosine, |u| <= pi/2, converged to double precision.
constexpr double cos_taylor(double u) {
    double u2 = u * u;
    double term = 1.0, sum = 1.0;
    for (int i = 1; i <= 12; ++i) {
        term *= -u2 / (double)((2 * i - 1) * (2 * i));
        sum += term;
    }
    return sum;
}

// cos(pi * t / 56) with exact integer range reduction (period t=112).
constexpr double cos_pi_over56(int t) {
    t %= 112;
    if (t < 0) t += 112;
    double sign = 1.0;
    if (t > 56) t = 112 - t;               // cos(2pi - x) = cos(x)
    if (t > 28) { t = 56 - t; sign = -1.0; } // cos(pi - x) = -cos(x)
    return sign * cos_taylor(K_PI * (double)t / 56.0);
}

struct Tables {
    float D[C_DIM][C_DIM];     // D[k][n]    = 2*cos(pi*(2n+1)k/56)
    float Dinv[C_DIM][C_DIM];  // Dinv[n][k] = cos(...)*(k==0?0.5:1)/28
};

constexpr Tables make_tables() {
    Tables t{};
    for (int k = 0; k < C_DIM; ++k) {
        for (int n = 0; n < C_DIM; ++n) {
            double c = cos_pi_over56((2 * n + 1) * k);
            t.D[k][n]    = (float)(2.0 * c);
            t.Dinv[n][k] = (float)(c * ((k == 0) ? 0.5 : 1.0) / (double)C_DIM);
        }
    }
    return t;
}

constexpr Tables TBL = make_tables();

} // namespace

// One thread = one pixel (b,h,w). x is [B,C,H,W]; weight is [H,W,C]; out is [B,C,H,W].
__global__ __launch_bounds__(256) void spedct_kernel(
    const float* __restrict__ x,
    const float* __restrict__ w,
    float* __restrict__ out) {

    const int p  = blockIdx.x * 256 + threadIdx.x; // pixel id over B*HW
    const int b  = p >> 16;      // / HW
    const int hw = p & 0xFFFF;   // % HW

    const float* xp = x + (size_t)b * (C_DIM * HW) + hw;

    // Channel vector: 28 coalesced dword loads (lanes contiguous in hw).
    float xv[C_DIM];
#pragma unroll
    for (int n = 0; n < C_DIM; ++n) xv[n] = xp[(size_t)n * HW];

    // Per-pixel weight row: 28 contiguous floats, 112 B = 16B aligned -> 7x float4.
    float wv[C_DIM];
    const float4* wp = (const float4*)(w + (size_t)hw * C_DIM);
#pragma unroll
    for (int i = 0; i < 7; ++i) {
        float4 v = wp[i];
        wv[4 * i + 0] = v.x; wv[4 * i + 1] = v.y;
        wv[4 * i + 2] = v.z; wv[4 * i + 3] = v.w;
    }

    // Xd = D * x  (n outer, k inner: 28 independent accumulator chains)
    float xd[C_DIM];
#pragma unroll
    for (int k = 0; k < C_DIM; ++k) xd[k] = 0.0f;
#pragma unroll
    for (int n = 0; n < C_DIM; ++n) {
        const float xn = xv[n];
#pragma unroll
        for (int k = 0; k < C_DIM; ++k)
            xd[k] = fmaf(TBL.D[k][n], xn, xd[k]);
    }

    // Spectral filter
#pragma unroll
    for (int k = 0; k < C_DIM; ++k) xd[k] *= wv[k];

    // out = Dinv * xd  (k outer, n inner: 28 independent accumulator chains)
    float o[C_DIM];
#pragma unroll
    for (int n = 0; n < C_DIM; ++n) o[n] = 0.0f;
#pragma unroll
    for (int k = 0; k < C_DIM; ++k) {
        const float xk = xd[k];
#pragma unroll
        for (int n = 0; n < C_DIM; ++n)
            o[n] = fmaf(TBL.Dinv[n][k], xk, o[n]);
    }

    // Coalesced dword stores per channel.
    float* op = out + (size_t)b * (C_DIM * HW) + hw;
#pragma unroll
    for (int n = 0; n < C_DIM; ++n) op[(size_t)n * HW] = o[n];
}

extern "C" void kernel_launch(void* const* d_in, const int* in_sizes, int n_in,
                              void* d_out, int out_size, void* d_ws, size_t ws_size,
                              hipStream_t stream) {
    const float* x = (const float*)d_in[0];   // [16,28,256,256]
    const float* w = (const float*)d_in[1];   // [256,256,28]
    float* out = (float*)d_out;               // [16,28,256,256]

    const int total_pixels = B_DIM * HW;      // 1,048,576
    dim3 block(256);
    dim3 grid(total_pixels / 256);            // 4096, exact
    spedct_kernel<<<grid, block, 0, stream>>>(x, w, out);
}

// Round 2
// 214.216 us; speedup vs baseline: 1.0066x; 1.0066x over previous
//
#include <hip/hip_runtime.h>

#define C_DIM 28
#define HW 65536   // 256*256
#define B_DIM 16
#define ITER 4     // pixels per thread, strided by 4*HW (so hw const, b advances by 4)
#define THREADS 256
#define GRID 1024  // 1024*256 threads * 4 px = 16*65536 pixels exactly

namespace {

constexpr double K_PI = 3.14159265358979323846;

constexpr double cos_taylor(double u) {
    double u2 = u * u;
    double term = 1.0, sum = 1.0;
    for (int i = 1; i <= 12; ++i) {
        term *= -u2 / (double)((2 * i - 1) * (2 * i));
        sum += term;
    }
    return sum;
}

// cos(pi * t / 56), exact integer range reduction (period 112).
constexpr double cos_pi_over56(int t) {
    t %= 112;
    if (t < 0) t += 112;
    double sign = 1.0;
    if (t > 56) t = 112 - t;
    if (t > 28) { t = 56 - t; sign = -1.0; }
    return sign * cos_taylor(K_PI * (double)t / 56.0);
}

struct Tables {
    float D[C_DIM][C_DIM];     // D[k][n]    = 2*cos(pi*(2n+1)k/56)
    float Dinv[C_DIM][C_DIM];  // Dinv[n][k] = cos(...)*(k==0?0.5:1)/28
};

constexpr Tables make_tables() {
    Tables t{};
    for (int k = 0; k < C_DIM; ++k) {
        for (int n = 0; n < C_DIM; ++n) {
            double c = cos_pi_over56((2 * n + 1) * k);
            t.D[k][n]    = (float)(2.0 * c);
            t.Dinv[n][k] = (float)(c * ((k == 0) ? 0.5 : 1.0) / (double)C_DIM);
        }
    }
    return t;
}

constexpr Tables TBL = make_tables();

} // namespace

// Thread t handles pixels p_i = t + i*(4*HW), i=0..3.
// hw = t & 0xFFFF is invariant across i; b = (t>>16) + 4*i.
// => weight row loaded ONCE per thread; x/out base advances by constant stride.
__global__ __launch_bounds__(256) void spedct_kernel(
    const float* __restrict__ x,
    const float* __restrict__ w,
    float* __restrict__ out) {

    const int t  = blockIdx.x * THREADS + threadIdx.x;  // 0..262143
    const int hw = t & (HW - 1);
    const int b0 = t >> 16;                             // 0..3

    // Weight row: 28 contiguous floats (112 B, 16B-aligned) -> 7x float4, once.
    float wv[C_DIM];
    const float4* wp4 = (const float4*)(w + (size_t)hw * C_DIM);
#pragma unroll
    for (int i = 0; i < 7; ++i) {
        float4 v = wp4[i];
        wv[4 * i + 0] = v.x; wv[4 * i + 1] = v.y;
        wv[4 * i + 2] = v.z; wv[4 * i + 3] = v.w;
    }

    const size_t bstride = (size_t)ITER * C_DIM * HW;   // elements between iterations
    const float* xp = x   + (size_t)b0 * C_DIM * HW + hw;
    float*       op = out + (size_t)b0 * C_DIM * HW + hw;

    // Double-buffered channel vector: prefetch i+1 while computing i.
    float xv[2][C_DIM];
#pragma unroll
    for (int n = 0; n < C_DIM; ++n) xv[0][n] = xp[(size_t)n * HW];

#pragma unroll
    for (int i = 0; i < ITER; ++i) {
        // Prefetch next pixel's channels (independent of current compute;
        // scheduler hoists these loads so they fly during the FMA block).
        if (i + 1 < ITER) {
            const float* xn = xp + (size_t)(i + 1) * bstride;
#pragma unroll
            for (int n = 0; n < C_DIM; ++n)
                xv[(i + 1) & 1][n] = xn[(size_t)n * HW];
        }

        const float* xc = xv[i & 1];

        // Xd = D * x : 28 independent FMA chains, constants as literals.
        float xd[C_DIM];
#pragma unroll
        for (int k = 0; k < C_DIM; ++k) xd[k] = TBL.D[k][0] * xc[0];
#pragma unroll
        for (int n = 1; n < C_DIM; ++n) {
            const float xn_ = xc[n];
#pragma unroll
            for (int k = 0; k < C_DIM; ++k)
                xd[k] = fmaf(TBL.D[k][n], xn_, xd[k]);
        }

        // Spectral filter.
#pragma unroll
        for (int k = 0; k < C_DIM; ++k) xd[k] *= wv[k];

        // out = Dinv * xd : 28 independent FMA chains.
        float o[C_DIM];
#pragma unroll
        for (int n = 0; n < C_DIM; ++n) o[n] = TBL.Dinv[n][0] * xd[0];
#pragma unroll
        for (int k = 1; k < C_DIM; ++k) {
            const float xk = xd[k];
#pragma unroll
            for (int n = 0; n < C_DIM; ++n)
                o[n] = fmaf(TBL.Dinv[n][k], xk, o[n]);
        }

        // Nontemporal stores: out is written once and never read this kernel;
        // keep L3 for x/w residency.
        float* oo = op + (size_t)i * bstride;
#pragma unroll
        for (int n = 0; n < C_DIM; ++n)
            __builtin_nontemporal_store(o[n], &oo[(size_t)n * HW]);
    }
}

extern "C" void kernel_launch(void* const* d_in, const int* in_sizes, int n_in,
                              void* d_out, int out_size, void* d_ws, size_t ws_size,
                              hipStream_t stream) {
    const float* x = (const float*)d_in[0];   // [16,28,256,256]
    const float* w = (const float*)d_in[1];   // [256,256,28]
    float* out = (float*)d_out;               // [16,28,256,256]

    spedct_kernel<<<dim3(GRID), dim3(THREADS), 0, stream>>>(x, w, out);
}